// Round 7
// baseline (175.390 us; speedup 1.0000x reference)
//
#include <hip/hip_runtime.h>

// VQ codebook lookup via MFMA on MI355X (gfx950).
// x: [32,64,64,64] f32 -> N=131072 rows, DIM=64; embed: [64, 512] f32.
// fp32 exactly decomposed into 3 bf16 planes (8+8+8 mantissa bits, truncation);
// dot = 6 cross-products accumulated in fp32 MFMA -> ~1e-6 error (fp32-grade).
// Outputs (flat f32): quantize [N*64], diff [1], embed_ind [N].
//
// R7: barrier-free main kernel, PAIRED col-tiles. Each iteration loads two
// tiles' B-fragments (24 x dwordx4, L2-resident) then runs two independent
// interleaved 24-MFMA chains (accA tile 2p, accB tile 2p+1). Per-tile
// summation order is bit-identical to the validated R3/R6 kernels -> same
// argmin. norms hoisted to registers before the loop (off critical path).

#define DIM      64
#define NCODE    512
#define NVEC     (32 * 64 * 64)   // 131072
#define WAVES    4
#define BLK      256
#define NCT      16               // col-tiles of 32 codes
#define CHUNK_DW 3072             // dwords per col-tile frag chunk (12 KB)

typedef unsigned int u32;
typedef __attribute__((ext_vector_type(8)))  short bf16x8;
typedef __attribute__((ext_vector_type(16))) float f32x16;

// Exact 3-plane bf16 split: v == hi + mid + lo (24 mantissa bits in 3x8).
__device__ __forceinline__ void split3(float v, u32& h, u32& m, u32& lo) {
    const u32 u = __float_as_uint(v);
    h = u >> 16;
    const float r1 = v - __uint_as_float(u & 0xFFFF0000u);
    const u32 u1 = __float_as_uint(r1);
    m = u1 >> 16;
    const float r2 = r1 - __uint_as_float(u1 & 0xFFFF0000u);
    lo = __float_as_uint(r2) >> 16;
}

// 16 blocks x 256 = 4096 threads: thread = (code c, 8-dim chunk g).
// Builds B-fragments (3 planes, MFMA frag layout), et transpose, f64 norms,
// and zeroes the diff output slot.  (Validated in R3/R6.)
__global__ void vq_prep(const float* __restrict__ embed,
                        u32* __restrict__ bfrag,
                        float* __restrict__ et,
                        float* __restrict__ norms,
                        float* __restrict__ out) {
    const int gid = blockIdx.x * BLK + threadIdx.x;   // [0, 4096)
    const int c = gid >> 3, g = gid & 7;
    const int s = g >> 1, kh = g & 1;                 // dims 16s + 8kh + j

    float v[8];
    double ns = 0.0;
    #pragma unroll
    for (int j = 0; j < 8; ++j) {
        v[j] = embed[(16 * s + 8 * kh + j) * NCODE + c];
        ns += (double)v[j] * (double)v[j];
    }
    // reduce squared norm across the 8 threads sharing code c (same wave)
    ns += __shfl_xor(ns, 1, 64);
    ns += __shfl_xor(ns, 2, 64);
    ns += __shfl_xor(ns, 4, 64);
    if (g == 0) norms[c] = (float)ns;

    u32 wH[4], wM[4], wL[4];
    #pragma unroll
    for (int q = 0; q < 4; ++q) {
        u32 h0, m0, l0, h1, m1, l1;
        split3(v[2 * q],     h0, m0, l0);
        split3(v[2 * q + 1], h1, m1, l1);
        wH[q] = h0 | (h1 << 16);
        wM[q] = m0 | (m1 << 16);
        wL[q] = l0 | (l1 << 16);
    }
    const int ct = c >> 5, lb = (c & 31) + 32 * kh;
    u32* base = bfrag + ct * CHUNK_DW;
    *reinterpret_cast<uint4*>(base + (0 * 4 + s) * 256 + lb * 4) =
        make_uint4(wH[0], wH[1], wH[2], wH[3]);
    *reinterpret_cast<uint4*>(base + (1 * 4 + s) * 256 + lb * 4) =
        make_uint4(wM[0], wM[1], wM[2], wM[3]);
    *reinterpret_cast<uint4*>(base + (2 * 4 + s) * 256 + lb * 4) =
        make_uint4(wL[0], wL[1], wL[2], wL[3]);

    // et transpose: et[c][d] = embed[d][c] for this thread's 8 dims
    float* ep = et + c * DIM + 16 * s + 8 * kh;
    *reinterpret_cast<float4*>(ep)     = make_float4(v[0], v[1], v[2], v[3]);
    *reinterpret_cast<float4*>(ep + 4) = make_float4(v[4], v[5], v[6], v[7]);

    if (gid == 0) out[(size_t)NVEC * DIM] = 0.0f;   // diff accumulator slot
}

__global__ __launch_bounds__(BLK, 2) void vq_main(
        const float* __restrict__ x,
        const u32* __restrict__ bfrag,
        const float* __restrict__ et,
        const float* __restrict__ norms,
        float* __restrict__ out) {
    __shared__ int sbk[WAVES][32];
    __shared__ float red[WAVES];

    const int tid = threadIdx.x;
    const int wid = tid >> 6, l = tid & 63;
    const int rl = l & 31, kh = l >> 5;
    const int n0 = (blockIdx.x * WAVES + wid) * 32;   // wave's 32 rows

    // ---- hoist norms: nrm[ct] for this lane's column (coalesced) ----
    float nrm[NCT];
    #pragma unroll
    for (int ct = 0; ct < NCT; ++ct) nrm[ct] = norms[ct * 32 + rl];

    // ---- A fragments: 32 rows x 64 dims, 3 planes x 4 k-steps, in VGPRs ----
    bf16x8 afr[3][4];
    {
        const float* xp = x + (size_t)(n0 + rl) * DIM + kh * 8;
        #pragma unroll
        for (int s = 0; s < 4; ++s) {
            const float4 va = *reinterpret_cast<const float4*>(xp + 16 * s);
            const float4 vb = *reinterpret_cast<const float4*>(xp + 16 * s + 4);
            const float v[8] = {va.x, va.y, va.z, va.w, vb.x, vb.y, vb.z, vb.w};
            #pragma unroll
            for (int q = 0; q < 4; ++q) {
                u32 h0, m0, l0, h1, m1, l1;
                split3(v[2 * q],     h0, m0, l0);
                split3(v[2 * q + 1], h1, m1, l1);
                afr[0][s][2 * q] = (short)h0;  afr[0][s][2 * q + 1] = (short)h1;
                afr[1][s][2 * q] = (short)m0;  afr[1][s][2 * q + 1] = (short)m1;
                afr[2][s][2 * q] = (short)l0;  afr[2][s][2 * q + 1] = (short)l1;
            }
        }
    }

    float best[16];
    int bk[16];
    #pragma unroll
    for (int r = 0; r < 16; ++r) { best[r] = __builtin_inff(); bk[r] = 0; }

    // ---- main loop: NO barriers, no LDS staging. Tiles processed in PAIRS
    //      with two independent MFMA chains (per-tile order == R3, bit-exact).
    const u32* fb = bfrag + (l << 2);   // lane base into frag layout
    for (int p = 0; p < NCT / 2; ++p) {
        const u32* tb0 = fb + (2 * p)     * CHUNK_DW;
        const u32* tb1 = fb + (2 * p + 1) * CHUNK_DW;
        bf16x8 b0[3][4], b1[3][4];
        #pragma unroll
        for (int s = 0; s < 4; ++s) {
            b0[0][s] = *reinterpret_cast<const bf16x8*>(tb0 + (0 * 4 + s) * 256);
            b1[0][s] = *reinterpret_cast<const bf16x8*>(tb1 + (0 * 4 + s) * 256);
            b0[1][s] = *reinterpret_cast<const bf16x8*>(tb0 + (1 * 4 + s) * 256);
            b1[1][s] = *reinterpret_cast<const bf16x8*>(tb1 + (1 * 4 + s) * 256);
            b0[2][s] = *reinterpret_cast<const bf16x8*>(tb0 + (2 * 4 + s) * 256);
            b1[2][s] = *reinterpret_cast<const bf16x8*>(tb1 + (2 * 4 + s) * 256);
        }

        f32x16 accA, accB;
        #pragma unroll
        for (int r = 0; r < 16; ++r) { accA[r] = 0.0f; accB[r] = 0.0f; }

        // two interleaved independent chains; per-tile s-major order == R3
        #pragma unroll
        for (int s = 0; s < 4; ++s) {
            accA = __builtin_amdgcn_mfma_f32_32x32x16_bf16(afr[0][s], b0[0][s], accA, 0, 0, 0);
            accB = __builtin_amdgcn_mfma_f32_32x32x16_bf16(afr[0][s], b1[0][s], accB, 0, 0, 0);
            accA = __builtin_amdgcn_mfma_f32_32x32x16_bf16(afr[0][s], b0[1][s], accA, 0, 0, 0);
            accB = __builtin_amdgcn_mfma_f32_32x32x16_bf16(afr[0][s], b1[1][s], accB, 0, 0, 0);
            accA = __builtin_amdgcn_mfma_f32_32x32x16_bf16(afr[1][s], b0[0][s], accA, 0, 0, 0);
            accB = __builtin_amdgcn_mfma_f32_32x32x16_bf16(afr[1][s], b1[0][s], accB, 0, 0, 0);
            accA = __builtin_amdgcn_mfma_f32_32x32x16_bf16(afr[1][s], b0[1][s], accA, 0, 0, 0);
            accB = __builtin_amdgcn_mfma_f32_32x32x16_bf16(afr[1][s], b1[1][s], accB, 0, 0, 0);
            accA = __builtin_amdgcn_mfma_f32_32x32x16_bf16(afr[0][s], b0[2][s], accA, 0, 0, 0);
            accB = __builtin_amdgcn_mfma_f32_32x32x16_bf16(afr[0][s], b1[2][s], accB, 0, 0, 0);
            accA = __builtin_amdgcn_mfma_f32_32x32x16_bf16(afr[2][s], b0[0][s], accA, 0, 0, 0);
            accB = __builtin_amdgcn_mfma_f32_32x32x16_bf16(afr[2][s], b1[0][s], accB, 0, 0, 0);
        }

        // argmin update in increasing-column order (tile 2p, then 2p+1)
        const int c0 = (2 * p) * 32 + rl;
        #pragma unroll
        for (int r = 0; r < 16; ++r) {
            const float sc = fmaf(-2.0f, accA[r], nrm[2 * p]);
            if (sc < best[r]) { best[r] = sc; bk[r] = c0; }
        }
        const int c1 = c0 + 32;
        #pragma unroll
        for (int r = 0; r < 16; ++r) {
            const float sc = fmaf(-2.0f, accB[r], nrm[2 * p + 1]);
            if (sc < best[r]) { best[r] = sc; bk[r] = c1; }
        }
    }

    // ---- cross-lane argmin over the 32 columns (lanes sharing kh), np tie-break ----
    #pragma unroll
    for (int off = 1; off <= 16; off <<= 1) {
        #pragma unroll
        for (int r = 0; r < 16; ++r) {
            const float ob = __shfl_xor(best[r], off, 64);
            const int obk  = __shfl_xor(bk[r], off, 64);
            if (ob < best[r] || (ob == best[r] && obk < bk[r])) { best[r] = ob; bk[r] = obk; }
        }
    }
    // C layout (m74/m101): row = (r&3) + 8*(r>>2) + 4*kh, col = lane&31
    if (rl == 0) {
        #pragma unroll
        for (int r = 0; r < 16; ++r) sbk[wid][(r & 3) + 8 * (r >> 2) + 4 * kh] = bk[r];
    }
    // sbk[wid] written and read only by wave wid -> wave-ordered LDS, no barrier.

    // ---- epilogue: coalesced quantize write + diff + indices ----
    float dp = 0.0f;
    const int rsub = l >> 4;            // 0..3
    const int dcol = (l & 15) * 4;      // 0..60
    #pragma unroll
    for (int i = 0; i < 8; ++i) {
        const int row = i * 4 + rsub;
        const int k = sbk[wid][row];
        const float4 q  = *reinterpret_cast<const float4*>(et + k * DIM + dcol);
        const float4 xv = *reinterpret_cast<const float4*>(x + (size_t)(n0 + row) * DIM + dcol);
        *reinterpret_cast<float4*>(out + (size_t)(n0 + row) * DIM + dcol) = q;
        const float d0 = q.x - xv.x, d1 = q.y - xv.y, d2 = q.z - xv.z, d3 = q.w - xv.w;
        dp = fmaf(d0, d0, dp); dp = fmaf(d1, d1, dp);
        dp = fmaf(d2, d2, dp); dp = fmaf(d3, d3, dp);
    }
    if (l < 32) out[(size_t)NVEC * DIM + 1 + n0 + l] = (float)sbk[wid][l];

    #pragma unroll
    for (int off = 32; off >= 1; off >>= 1) dp += __shfl_down(dp, off, 64);
    if (l == 0) red[wid] = dp;
    __syncthreads();
    if (tid == 0) {
        const float s = (red[0] + red[1]) + (red[2] + red[3]);
        atomicAdd(out + (size_t)NVEC * DIM, s * (1.0f / ((float)NVEC * (float)DIM)));
    }
}

extern "C" void kernel_launch(void* const* d_in, const int* in_sizes, int n_in,
                              void* d_out, int out_size, void* d_ws, size_t ws_size,
                              hipStream_t stream) {
    const float* x     = (const float*)d_in[0];
    const float* embed = (const float*)d_in[1];
    float* out = (float*)d_out;

    u32* bfrag   = (u32*)d_ws;                       // 16*3072 dwords = 192 KB
    float* et    = (float*)d_ws + NCT * CHUNK_DW;    // 512*64 f32 = 128 KB
    float* norms = et + (size_t)NCODE * DIM;         // 512 f32

    vq_prep<<<16, BLK, 0, stream>>>(embed, bfrag, et, norms, out);
    vq_main<<<NVEC / (WAVES * 32), BLK, 0, stream>>>(x, bfrag, et, norms, out);
}

// Round 8
// 141.590 us; speedup vs baseline: 1.2387x; 1.2387x over previous
//
#include <hip/hip_runtime.h>

// VQ codebook lookup via MFMA on MI355X (gfx950).
// x: [32,64,64,64] f32 -> N=131072 rows, DIM=64; embed: [64, 512] f32.
// fp32 exactly decomposed into 3 bf16 planes (8+8+8 mantissa bits, truncation);
// dot = 6 cross-products accumulated in fp32 MFMA -> ~1e-6 error (fp32-grade).
// Outputs (flat f32): quantize [N*64], diff [1], embed_ind [N].
//
// R8: barrier-free global-direct, schedule PINNED. Fully-unrolled 16-tile
// loop, alternating named register sets s0/s1:
//   [issue 12 loads tile t+1] [sched_barrier(0)] [setprio(1) 24-MFMA tile t
//   setprio(0)] [argmin] [sched_barrier(0)] ...
// The named-set WAR dep + fences force 12 loads in flight across each MFMA
// chain (R6/R7 failed because the register allocator issued loads just
// before use -> full L2 latency per MFMA group; VGPR_Count 64/84 proved it).
// MFMA chain order bit-identical to validated R3 -> same argmin.

#define DIM      64
#define NCODE    512
#define NVEC     (32 * 64 * 64)   // 131072
#define WAVES    4
#define BLK      256
#define NCT      16               // col-tiles of 32 codes
#define CHUNK_DW 3072             // dwords per col-tile frag chunk (12 KB)

typedef unsigned int u32;
typedef __attribute__((ext_vector_type(8)))  short bf16x8;
typedef __attribute__((ext_vector_type(16))) float f32x16;

// Exact 3-plane bf16 split: v == hi + mid + lo (24 mantissa bits in 3x8).
__device__ __forceinline__ void split3(float v, u32& h, u32& m, u32& lo) {
    const u32 u = __float_as_uint(v);
    h = u >> 16;
    const float r1 = v - __uint_as_float(u & 0xFFFF0000u);
    const u32 u1 = __float_as_uint(r1);
    m = u1 >> 16;
    const float r2 = r1 - __uint_as_float(u1 & 0xFFFF0000u);
    lo = __float_as_uint(r2) >> 16;
}

// 16 blocks x 256 = 4096 threads: thread = (code c, 8-dim chunk g).
// Builds B-fragments (3 planes, MFMA frag layout), et transpose, f64 norms,
// and zeroes the diff output slot.  (Validated R3/R6/R7.)
__global__ void vq_prep(const float* __restrict__ embed,
                        u32* __restrict__ bfrag,
                        float* __restrict__ et,
                        float* __restrict__ norms,
                        float* __restrict__ out) {
    const int gid = blockIdx.x * BLK + threadIdx.x;   // [0, 4096)
    const int c = gid >> 3, g = gid & 7;
    const int s = g >> 1, kh = g & 1;                 // dims 16s + 8kh + j

    float v[8];
    double ns = 0.0;
    #pragma unroll
    for (int j = 0; j < 8; ++j) {
        v[j] = embed[(16 * s + 8 * kh + j) * NCODE + c];
        ns += (double)v[j] * (double)v[j];
    }
    ns += __shfl_xor(ns, 1, 64);
    ns += __shfl_xor(ns, 2, 64);
    ns += __shfl_xor(ns, 4, 64);
    if (g == 0) norms[c] = (float)ns;

    u32 wH[4], wM[4], wL[4];
    #pragma unroll
    for (int q = 0; q < 4; ++q) {
        u32 h0, m0, l0, h1, m1, l1;
        split3(v[2 * q],     h0, m0, l0);
        split3(v[2 * q + 1], h1, m1, l1);
        wH[q] = h0 | (h1 << 16);
        wM[q] = m0 | (m1 << 16);
        wL[q] = l0 | (l1 << 16);
    }
    const int ct = c >> 5, lb = (c & 31) + 32 * kh;
    u32* base = bfrag + ct * CHUNK_DW;
    *reinterpret_cast<uint4*>(base + (0 * 4 + s) * 256 + lb * 4) =
        make_uint4(wH[0], wH[1], wH[2], wH[3]);
    *reinterpret_cast<uint4*>(base + (1 * 4 + s) * 256 + lb * 4) =
        make_uint4(wM[0], wM[1], wM[2], wM[3]);
    *reinterpret_cast<uint4*>(base + (2 * 4 + s) * 256 + lb * 4) =
        make_uint4(wL[0], wL[1], wL[2], wL[3]);

    float* ep = et + c * DIM + 16 * s + 8 * kh;
    *reinterpret_cast<float4*>(ep)     = make_float4(v[0], v[1], v[2], v[3]);
    *reinterpret_cast<float4*>(ep + 4) = make_float4(v[4], v[5], v[6], v[7]);

    if (gid == 0) out[(size_t)NVEC * DIM] = 0.0f;   // diff accumulator slot
}

// 24-MFMA chain for one tile, s-major order == validated R3 (bit-exact).
#define TILE_MFMA(bset, acc)                                                       \
    _Pragma("unroll")                                                              \
    for (int s = 0; s < 4; ++s) {                                                  \
        acc = __builtin_amdgcn_mfma_f32_32x32x16_bf16(afr[0][s], bset[0 + s], acc, 0, 0, 0); \
        acc = __builtin_amdgcn_mfma_f32_32x32x16_bf16(afr[0][s], bset[4 + s], acc, 0, 0, 0); \
        acc = __builtin_amdgcn_mfma_f32_32x32x16_bf16(afr[1][s], bset[0 + s], acc, 0, 0, 0); \
        acc = __builtin_amdgcn_mfma_f32_32x32x16_bf16(afr[1][s], bset[4 + s], acc, 0, 0, 0); \
        acc = __builtin_amdgcn_mfma_f32_32x32x16_bf16(afr[0][s], bset[8 + s], acc, 0, 0, 0); \
        acc = __builtin_amdgcn_mfma_f32_32x32x16_bf16(afr[2][s], bset[0 + s], acc, 0, 0, 0); \
    }

#define LOAD_SET(dst, tile)                                                        \
    {                                                                              \
        const u32* tb_ = fb + (tile) * CHUNK_DW;                                   \
        _Pragma("unroll")                                                          \
        for (int j = 0; j < 12; ++j)                                               \
            dst[j] = *reinterpret_cast<const bf16x8*>(tb_ + j * 256);              \
    }

#define ARGMIN_UPDATE(acc, ct)                                                     \
    {                                                                              \
        const int col_ = (ct) * 32 + rl;                                           \
        _Pragma("unroll")                                                          \
        for (int r = 0; r < 16; ++r) {                                             \
            const float sc_ = fmaf(-2.0f, acc[r], nrm[ct]);                        \
            if (sc_ < best[r]) { best[r] = sc_; bk[r] = col_; }                    \
        }                                                                          \
    }

__global__ __launch_bounds__(BLK, 2) void vq_main(
        const float* __restrict__ x,
        const u32* __restrict__ bfrag,
        const float* __restrict__ et,
        const float* __restrict__ norms,
        float* __restrict__ out) {
    __shared__ int sbk[WAVES][32];
    __shared__ float red[WAVES];

    const int tid = threadIdx.x;
    const int wid = tid >> 6, l = tid & 63;
    const int rl = l & 31, kh = l >> 5;
    const int n0 = (blockIdx.x * WAVES + wid) * 32;   // wave's 32 rows

    // hoisted per-lane norms (constant-indexed after full unroll)
    float nrm[NCT];
    #pragma unroll
    for (int ct = 0; ct < NCT; ++ct) nrm[ct] = norms[ct * 32 + rl];

    // A fragments: 32 rows x 64 dims, 3 planes x 4 k-steps, in VGPRs
    bf16x8 afr[3][4];
    {
        const float* xp = x + (size_t)(n0 + rl) * DIM + kh * 8;
        #pragma unroll
        for (int s = 0; s < 4; ++s) {
            const float4 va = *reinterpret_cast<const float4*>(xp + 16 * s);
            const float4 vb = *reinterpret_cast<const float4*>(xp + 16 * s + 4);
            const float v[8] = {va.x, va.y, va.z, va.w, vb.x, vb.y, vb.z, vb.w};
            #pragma unroll
            for (int q = 0; q < 4; ++q) {
                u32 h0, m0, l0, h1, m1, l1;
                split3(v[2 * q],     h0, m0, l0);
                split3(v[2 * q + 1], h1, m1, l1);
                afr[0][s][2 * q] = (short)h0;  afr[0][s][2 * q + 1] = (short)h1;
                afr[1][s][2 * q] = (short)m0;  afr[1][s][2 * q + 1] = (short)m1;
                afr[2][s][2 * q] = (short)l0;  afr[2][s][2 * q + 1] = (short)l1;
            }
        }
    }

    float best[16];
    int bk[16];
    #pragma unroll
    for (int r = 0; r < 16; ++r) { best[r] = __builtin_inff(); bk[r] = 0; }

    const u32* fb = bfrag + (l << 2);   // lane base into frag layout
    bf16x8 s0[12], s1[12];

    // prologue: tile 0 into s0
    LOAD_SET(s0, 0)
    __builtin_amdgcn_sched_barrier(0);

    // fully-unrolled pinned pipeline: phase computes tile t from one set
    // while the other set's 12 loads (tile t+1) are in flight.
    #pragma unroll
    for (int p = 0; p < 8; ++p) {
        // ---- phase A: compute tile 2p (s0), prefetch 2p+1 -> s1 ----
        LOAD_SET(s1, 2 * p + 1)
        __builtin_amdgcn_sched_barrier(0);
        {
            f32x16 acc;
            #pragma unroll
            for (int r = 0; r < 16; ++r) acc[r] = 0.0f;
            __builtin_amdgcn_s_setprio(1);
            TILE_MFMA(s0, acc)
            __builtin_amdgcn_s_setprio(0);
            ARGMIN_UPDATE(acc, 2 * p)
        }
        __builtin_amdgcn_sched_barrier(0);

        // ---- phase B: compute tile 2p+1 (s1), prefetch 2p+2 -> s0 ----
        if (p < 7) {
            LOAD_SET(s0, 2 * p + 2)
        }
        __builtin_amdgcn_sched_barrier(0);
        {
            f32x16 acc;
            #pragma unroll
            for (int r = 0; r < 16; ++r) acc[r] = 0.0f;
            __builtin_amdgcn_s_setprio(1);
            TILE_MFMA(s1, acc)
            __builtin_amdgcn_s_setprio(0);
            ARGMIN_UPDATE(acc, 2 * p + 1)
        }
        __builtin_amdgcn_sched_barrier(0);
    }

    // ---- cross-lane argmin over the 32 columns (lanes sharing kh), np tie-break ----
    #pragma unroll
    for (int off = 1; off <= 16; off <<= 1) {
        #pragma unroll
        for (int r = 0; r < 16; ++r) {
            const float ob = __shfl_xor(best[r], off, 64);
            const int obk  = __shfl_xor(bk[r], off, 64);
            if (ob < best[r] || (ob == best[r] && obk < bk[r])) { best[r] = ob; bk[r] = obk; }
        }
    }
    // C layout (m74/m101): row = (r&3) + 8*(r>>2) + 4*kh, col = lane&31
    if (rl == 0) {
        #pragma unroll
        for (int r = 0; r < 16; ++r) sbk[wid][(r & 3) + 8 * (r >> 2) + 4 * kh] = bk[r];
    }
    // sbk[wid] written and read only by wave wid -> wave-ordered LDS, no barrier.

    // ---- epilogue: coalesced quantize write + diff + indices ----
    float dp = 0.0f;
    const int rsub = l >> 4;            // 0..3
    const int dcol = (l & 15) * 4;      // 0..60
    #pragma unroll
    for (int i = 0; i < 8; ++i) {
        const int row = i * 4 + rsub;
        const int k = sbk[wid][row];
        const float4 q  = *reinterpret_cast<const float4*>(et + k * DIM + dcol);
        const float4 xv = *reinterpret_cast<const float4*>(x + (size_t)(n0 + row) * DIM + dcol);
        *reinterpret_cast<float4*>(out + (size_t)(n0 + row) * DIM + dcol) = q;
        const float d0 = q.x - xv.x, d1 = q.y - xv.y, d2 = q.z - xv.z, d3 = q.w - xv.w;
        dp = fmaf(d0, d0, dp); dp = fmaf(d1, d1, dp);
        dp = fmaf(d2, d2, dp); dp = fmaf(d3, d3, dp);
    }
    if (l < 32) out[(size_t)NVEC * DIM + 1 + n0 + l] = (float)sbk[wid][l];

    #pragma unroll
    for (int off = 32; off >= 1; off >>= 1) dp += __shfl_down(dp, off, 64);
    if (l == 0) red[wid] = dp;
    __syncthreads();
    if (tid == 0) {
        const float s = (red[0] + red[1]) + (red[2] + red[3]);
        atomicAdd(out + (size_t)NVEC * DIM, s * (1.0f / ((float)NVEC * (float)DIM)));
    }
}

extern "C" void kernel_launch(void* const* d_in, const int* in_sizes, int n_in,
                              void* d_out, int out_size, void* d_ws, size_t ws_size,
                              hipStream_t stream) {
    const float* x     = (const float*)d_in[0];
    const float* embed = (const float*)d_in[1];
    float* out = (float*)d_out;

    u32* bfrag   = (u32*)d_ws;                       // 16*3072 dwords = 192 KB
    float* et    = (float*)d_ws + NCT * CHUNK_DW;    // 512*64 f32 = 128 KB
    float* norms = et + (size_t)NCODE * DIM;         // 512 f32

    vq_prep<<<16, BLK, 0, stream>>>(embed, bfrag, et, norms, out);
    vq_main<<<NVEC / (WAVES * 32), BLK, 0, stream>>>(x, bfrag, et, norms, out);
}